// Round 1
// baseline (593.798 us; speedup 1.0000x reference)
//
#include <hip/hip_runtime.h>
#include <math.h>

// Problem constants (fixed by reference)
#define NN   10000
#define EE   160000
#define GG   128
#define HIDK 25
#define KE   26      // 25 MLP features + 1 constant row for b2
#define DOUT 32
#define EPSBN 1e-5f

// ---------------- workspace layout (float offsets) ----------------
// zeroed region (one hipMemsetAsync):
#define OFF_MO    0          // 12 used (s1[3], s2[6->stored as 6 pairs.. we use 9])
#define OFF_DEG   16         // N
#define OFF_AGG0  10016      // N*32
#define OFF_AGG1  330016     // N*32
#define OFF_GSUM  650016     // G*32
#define OFF_GCNT  654112     // G
#define ZERO_FLOATS 654240
// non-zeroed:
#define OFF_W1F   654240     // 75 (padded 80)
#define OFF_B1F   654320     // 25 (padded 32)
#define OFF_Z     654352     // N*26*32 = 8,320,000
#define OFF_X1    8974352    // N*32
#define OFF_X2    9294352    // N*32
#define TOTAL_FLOATS 9614352 // ~38.5 MB of d_ws

__device__ inline float wave_red(float v) {
    for (int off = 32; off; off >>= 1) v += __shfl_down(v, off);
    return v;
}

// ---- edge_attr moments: s1[c], s2[c,d] (9 entries, symmetric stored full-ish)
__global__ void k_moments(const float* __restrict__ ea, float* __restrict__ mo) {
    float s[9];
#pragma unroll
    for (int j = 0; j < 9; j++) s[j] = 0.f;
    int stride = gridDim.x * blockDim.x;
    for (int e = blockIdx.x * blockDim.x + threadIdx.x; e < EE; e += stride) {
        float a0 = ea[3 * e], a1 = ea[3 * e + 1], a2 = ea[3 * e + 2];
        s[0] += a0; s[1] += a1; s[2] += a2;
        s[3] += a0 * a0; s[4] += a0 * a1; s[5] += a0 * a2;
        s[6] += a1 * a1; s[7] += a1 * a2; s[8] += a2 * a2;
    }
#pragma unroll
    for (int j = 0; j < 9; j++) {
        float r = wave_red(s[j]);
        if ((threadIdx.x & 63) == 0) atomicAdd(mo + j, r);
    }
}

// ---- in-degree (dst) counts
__global__ void k_deg(const int* __restrict__ ei, float* __restrict__ deg) {
    int e = blockIdx.x * blockDim.x + threadIdx.x;
    if (e < EE) atomicAdd(deg + ei[EE + e], 1.0f);
}

// ---- fold BN (analytic stats) into w1', b1'
__global__ void k_fold(const float* __restrict__ mo, const float* __restrict__ w1,
                       const float* __restrict__ b1, const float* __restrict__ g,
                       const float* __restrict__ be, float* __restrict__ w1f,
                       float* __restrict__ b1f) {
    int j = threadIdx.x;
    if (j >= HIDK) return;
    const float inv = 1.0f / (float)EE;
    float m0 = mo[0] * inv, m1 = mo[1] * inv, m2 = mo[2] * inv;
    float c00 = mo[3] * inv - m0 * m0, c01 = mo[4] * inv - m0 * m1, c02 = mo[5] * inv - m0 * m2;
    float c11 = mo[6] * inv - m1 * m1, c12 = mo[7] * inv - m1 * m2, c22 = mo[8] * inv - m2 * m2;
    float w0 = w1[j], wa = w1[25 + j], wb = w1[50 + j];
    float mean = m0 * w0 + m1 * wa + m2 * wb + b1[j];
    float var = w0 * w0 * c00 + wa * wa * c11 + wb * wb * c22
              + 2.f * (w0 * wa * c01 + w0 * wb * c02 + wa * wb * c12);
    float sc = g[j] * rsqrtf(var + EPSBN);
    w1f[j] = w0 * sc; w1f[25 + j] = wa * sc; w1f[50 + j] = wb * sc;
    b1f[j] = (b1[j] - mean) * sc + be[j];
}

// ---- per-node z[n,k,o] = sum_i x[n,i]*w2[k,i,o]; row 25 = x@b2
template <int DIN>
__global__ void k_z(const float* __restrict__ x, const float* __restrict__ w2,
                    const float* __restrict__ b2, float* __restrict__ z) {
    int t = threadIdx.x;
    int n = blockIdx.x * 8 + (t >> 5);
    int o = t & 31;
    if (n >= NN) return;
    float xr[DIN];
#pragma unroll
    for (int i = 0; i < DIN; i++) xr[i] = x[n * DIN + i];
    float* zp = z + (size_t)n * (KE * DOUT) + o;
    for (int k = 0; k < HIDK; k++) {
        const float* wp = w2 + k * (DIN * DOUT) + o;
        float acc = 0.f;
#pragma unroll
        for (int i = 0; i < DIN; i++) acc += xr[i] * wp[i * DOUT];
        zp[k * DOUT] = acc;
    }
    float acc = 0.f;
#pragma unroll
    for (int i = 0; i < DIN; i++) acc += xr[i] * b2[i * DOUT + o];
    zp[HIDK * DOUT] = acc;
}

// ---- edge kernel: h = relu(ea@w1'+b1'); msg = h . z[src]; atomic scatter to agg[dst]
__global__ void k_edge(const float* __restrict__ ea, const int* __restrict__ ei,
                       const float* __restrict__ w1f, const float* __restrict__ b1f,
                       const float* __restrict__ z, float* __restrict__ agg) {
    __shared__ float hsh[8][KE];
    __shared__ int ssrc[8], sdst[8];
    int t = threadIdx.x;
    int eb = blockIdx.x * 8;
    if (t < 8 * KE) {
        int el = t / KE, k = t - el * KE;
        int e = eb + el;
        float v = 1.0f;
        if (e < EE && k < HIDK) {
            v = ea[3 * e] * w1f[k] + ea[3 * e + 1] * w1f[25 + k] + ea[3 * e + 2] * w1f[50 + k] + b1f[k];
            v = v > 0.f ? v : 0.f;
        }
        hsh[el][k] = v;
    }
    if (t < 8) {
        int e = eb + t;
        ssrc[t] = (e < EE) ? ei[e] : 0;
        sdst[t] = (e < EE) ? ei[EE + e] : 0;
    }
    __syncthreads();
    int el = t >> 5, o = t & 31;
    int e = eb + el;
    if (e >= EE) return;
    const float* zp = z + (size_t)ssrc[el] * (KE * DOUT) + o;
    float acc = 0.f;
#pragma unroll
    for (int k = 0; k < KE; k++) acc += hsh[el][k] * zp[k * DOUT];
    atomicAdd(agg + sdst[el] * DOUT + o, acc);
}

// ---- node update: x_out = elu(agg/deg + x@wr + bc)
template <int DIN>
__global__ void k_node(const float* __restrict__ agg, const float* __restrict__ deg,
                       const float* __restrict__ xin, const float* __restrict__ wr,
                       const float* __restrict__ bc, float* __restrict__ xout) {
    int idx = blockIdx.x * blockDim.x + threadIdx.x;
    if (idx >= NN * DOUT) return;
    int n = idx >> 5, o = idx & 31;
    float d = deg[n]; d = d < 1.f ? 1.f : d;
    float acc = agg[idx] / d + bc[o];
#pragma unroll
    for (int i = 0; i < DIN; i++) acc += xin[n * DIN + i] * wr[i * DOUT + o];
    xout[idx] = acc > 0.f ? acc : expm1f(acc);
}

// ---- global mean pool accumulation
__global__ void k_pool(const float* __restrict__ x, const int* __restrict__ batch,
                       float* __restrict__ gsum, float* __restrict__ gcnt) {
    int idx = blockIdx.x * blockDim.x + threadIdx.x;
    if (idx >= NN * DOUT) return;
    int n = idx >> 5, o = idx & 31;
    int b = batch[n];
    atomicAdd(gsum + b * DOUT + o, x[idx]);
    if (o == 0) atomicAdd(gcnt + b, 1.0f);
}

// ---- final fc
__global__ void k_fc(const float* __restrict__ gsum, const float* __restrict__ gcnt,
                     const float* __restrict__ wfc, const float* __restrict__ bfc,
                     float* __restrict__ out) {
    int g = threadIdx.x;
    if (g >= GG) return;
    float c = gcnt[g]; c = c < 1.f ? 1.f : c;
    float acc = 0.f;
#pragma unroll
    for (int o = 0; o < DOUT; o++) acc += gsum[g * DOUT + o] * wfc[o];
    out[g] = acc / c + bfc[0];
}

extern "C" void kernel_launch(void* const* d_in, const int* in_sizes, int n_in,
                              void* d_out, int out_size, void* d_ws, size_t ws_size,
                              hipStream_t stream) {
    const float* x     = (const float*)d_in[0];
    const float* ea    = (const float*)d_in[1];
    const int*   ei    = (const int*)d_in[2];
    const int*   batch = (const int*)d_in[3];
    const float* w1_0 = (const float*)d_in[4];
    const float* b1_0 = (const float*)d_in[5];
    const float* g_0  = (const float*)d_in[6];
    const float* be_0 = (const float*)d_in[7];
    const float* w2_0 = (const float*)d_in[8];
    const float* b2_0 = (const float*)d_in[9];
    const float* wr_0 = (const float*)d_in[10];
    const float* bc_0 = (const float*)d_in[11];
    const float* w1_1 = (const float*)d_in[12];
    const float* b1_1 = (const float*)d_in[13];
    const float* g_1  = (const float*)d_in[14];
    const float* be_1 = (const float*)d_in[15];
    const float* w2_1 = (const float*)d_in[16];
    const float* b2_1 = (const float*)d_in[17];
    const float* wr_1 = (const float*)d_in[18];
    const float* bc_1 = (const float*)d_in[19];
    const float* wfc  = (const float*)d_in[20];
    const float* bfc  = (const float*)d_in[21];

    float* ws   = (float*)d_ws;
    float* mo   = ws + OFF_MO;
    float* deg  = ws + OFF_DEG;
    float* agg0 = ws + OFF_AGG0;
    float* agg1 = ws + OFF_AGG1;
    float* gsum = ws + OFF_GSUM;
    float* gcnt = ws + OFF_GCNT;
    float* w1f  = ws + OFF_W1F;
    float* b1f  = ws + OFF_B1F;
    float* z    = ws + OFF_Z;
    float* x1   = ws + OFF_X1;
    float* x2   = ws + OFF_X2;

    hipMemsetAsync(ws, 0, (size_t)ZERO_FLOATS * sizeof(float), stream);

    k_moments<<<256, 256, 0, stream>>>(ea, mo);
    k_deg<<<(EE + 255) / 256, 256, 0, stream>>>(ei, deg);

    // ---- layer 0 (din=16)
    k_fold<<<1, 64, 0, stream>>>(mo, w1_0, b1_0, g_0, be_0, w1f, b1f);
    k_z<16><<<(NN + 7) / 8, 256, 0, stream>>>(x, w2_0, b2_0, z);
    k_edge<<<(EE + 7) / 8, 256, 0, stream>>>(ea, ei, w1f, b1f, z, agg0);
    k_node<16><<<(NN * DOUT + 255) / 256, 256, 0, stream>>>(agg0, deg, x, wr_0, bc_0, x1);

    // ---- layer 1 (din=32)
    k_fold<<<1, 64, 0, stream>>>(mo, w1_1, b1_1, g_1, be_1, w1f, b1f);
    k_z<32><<<(NN + 7) / 8, 256, 0, stream>>>(x1, w2_1, b2_1, z);
    k_edge<<<(EE + 7) / 8, 256, 0, stream>>>(ea, ei, w1f, b1f, z, agg1);
    k_node<32><<<(NN * DOUT + 255) / 256, 256, 0, stream>>>(agg1, deg, x1, wr_1, bc_1, x2);

    // ---- pool + fc
    k_pool<<<(NN * DOUT + 255) / 256, 256, 0, stream>>>(x2, batch, gsum, gcnt);
    k_fc<<<1, 128, 0, stream>>>(gsum, gcnt, wfc, bfc, (float*)d_out);
}